// Round 12
// baseline (368.621 us; speedup 1.0000x reference)
//
#include <hip/hip_runtime.h>
#include <hip/hip_bf16.h>

typedef unsigned short u16;
typedef unsigned int u32;
typedef __attribute__((ext_vector_type(8))) short short8;
typedef __attribute__((ext_vector_type(4))) float f32x4;

#define B_ 4
#define T_ 1024
#define E_ 1024
#define NH 16
#define HD 1024
#define JTOT 2048
#define SCALE 0.125f
#define LOG2E 1.44269504f

// ---------- helpers ----------
__device__ __forceinline__ u16 f2b(float f) {
  u32 x = __float_as_uint(f);
  u32 r = (x + 0x7fffu + ((x >> 16) & 1u)) >> 16;  // RNE
  return (u16)r;
}
__device__ __forceinline__ u16 f2b_fast(float f) {  // round-half-up (2 ops)
  return (u16)((__float_as_uint(f) + 0x8000u) >> 16);
}
__device__ __forceinline__ float b2f(u16 b) {
  return __uint_as_float((u32)b << 16);
}
__device__ __forceinline__ float fexp2(float x) {
  float r;
  asm("v_exp_f32 %0, %1" : "=v"(r) : "v"(x));
  return r;
}
__device__ __forceinline__ u32 cvtpk(float lo, float hi) {  // bf16 pair: lo in low 16
  u32 r;
  asm("v_cvt_pk_bf16_f32 %0, %1, %2" : "=v"(r) : "v"(lo), "v"(hi));
  return r;
}

__device__ __forceinline__ void gload_lds16(const void* g, void* l) {
  __builtin_amdgcn_global_load_lds((const __attribute__((address_space(1))) u32*)g,
                                   (__attribute__((address_space(3))) u32*)l, 16, 0, 0);
}

__device__ __forceinline__ short8 pack8(float4 f0, float4 f1) {
  short8 o;
  o[0] = (short)f2b(f0.x); o[1] = (short)f2b(f0.y);
  o[2] = (short)f2b(f0.z); o[3] = (short)f2b(f0.w);
  o[4] = (short)f2b(f1.x); o[5] = (short)f2b(f1.y);
  o[6] = (short)f2b(f1.z); o[7] = (short)f2b(f1.w);
  return o;
}

// ---------- fused conversions: x->bf16 | W-transpose x4 | xl->kt | xl->vT ----------
// kt/vt tiles stored UNSWIZZLED now (consumed via global reads: no LDS bank concerns)
__global__ __launch_bounds__(256) void cvt_all(
    const float* __restrict__ x, const float* __restrict__ Wq, const float* __restrict__ Wk,
    const float* __restrict__ Wv, const float* __restrict__ Wo, const float* __restrict__ xl,
    u16* __restrict__ xb, u16* __restrict__ wqkvT, u16* __restrict__ woT,
    u16* __restrict__ kt, u16* __restrict__ vt) {
  int bx = blockIdx.x;
  if (bx < 2048) {  // x -> xb (bf16)
    int i = bx * 256 + threadIdx.x;
    const float4* p = (const float4*)x + (size_t)i * 2;
    ((short8*)xb)[i] = pack8(p[0], p[1]);
  } else if (bx < 3072) {  // 4x W -> WT bf16 transposed
    __shared__ float tile[64][65];
    int idx = bx - 2048;
    int z = idx >> 8, yy = (idx >> 4) & 15, xx = idx & 15;
    const float* W;
    u16* WT;
    if (z == 0) { W = Wq; WT = wqkvT; }
    else if (z == 1) { W = Wk; WT = wqkvT + (size_t)1024 * 1024; }
    else if (z == 2) { W = Wv; WT = wqkvT + (size_t)2048 * 1024; }
    else { W = Wo; WT = woT; }
    int t = threadIdx.x;
    int r0 = yy * 64, c0 = xx * 64;
#pragma unroll
    for (int i = 0; i < 16; ++i) {
      int r = i * 4 + (t >> 6), c = t & 63;
      tile[r][c] = W[(size_t)(r0 + r) * 1024 + c0 + c];
    }
    __syncthreads();
#pragma unroll
    for (int i = 0; i < 16; ++i) {
      int r = i * 4 + (t >> 6), c = t & 63;
      WT[(size_t)(c0 + r) * 1024 + r0 + c] = f2b(tile[c][r]);
    }
  } else if (bx < 5120) {  // xl k-half -> kt tiles jc 0..15 [64 j][64 d]
    int i = (bx - 3072) * 256 + threadIdx.x;
    int hd8 = i & 127, j = (i >> 7) & 1023, b = i >> 17;
    const float4* p = (const float4*)(xl + ((((size_t)b * 1024 + j) * 2 + 0) * 1024 + (size_t)hd8 * 8));
    short8 o = pack8(p[0], p[1]);
    int h = hd8 >> 3, d0 = (hd8 & 7) * 8;
    int jc = j >> 6, jl = j & 63;
    u16* dst = kt + (((size_t)(b * 16 + h) * 32 + jc) * 4096) + jl * 64 + d0;
    *(short8*)dst = o;
  } else {  // xl v-half -> vt tiles jc 0..15 [64 d][64 j] (transposed)
    __shared__ u16 Vl[64 * 72];
    int bxx = bx - 5120;
    int jc = bxx & 15, h = (bxx >> 4) & 15, b = bxx >> 8;
    int t = threadIdx.x;
    int j0 = jc * 64;
#pragma unroll
    for (int it = 0; it < 2; ++it) {
      int p = t + 256 * it;
      int j = p >> 3, d8 = p & 7;
      const float4* src = (const float4*)(xl + ((((size_t)b * 1024 + j0 + j) * 2 + 1) * 1024 + h * 64 + (size_t)d8 * 8));
      *(short8*)&Vl[j * 72 + d8 * 8] = pack8(src[0], src[1]);
    }
    __syncthreads();
#pragma unroll
    for (int it = 0; it < 2; ++it) {
      int p = t + 256 * it;
      int d = p >> 3, j8 = p & 7;
      short8 o;
#pragma unroll
      for (int e = 0; e < 8; ++e) o[e] = (short)Vl[(j8 * 8 + e) * 72 + d];
      u16* dst = vt + (((size_t)(b * 16 + h) * 32 + jc) * 4096) + d * 64 + j8 * 8;
      *(short8*)dst = o;
    }
  }
}

// ---------- QKV GEMM: 128x128 tiles, coalesced-only epilogue, XCD column strips ----------
__global__ __launch_bounds__(256) void gemm_qkv(
    const u16* __restrict__ A, const u16* __restrict__ BT,
    const float* __restrict__ b0, const float* __restrict__ b1, const float* __restrict__ b2,
    u16* __restrict__ qb, u16* __restrict__ kbp, u16* __restrict__ vb) {
  __shared__ __align__(16) u16 As[128 * 32];
  __shared__ __align__(16) u16 Bs[128 * 32];
  const int t = threadIdx.x;
  const int lane = t & 63, wv = t >> 6;
  const int wr = wv >> 1, wc = wv & 1;
  const int xcd = blockIdx.x & 7, loc = blockIdx.x >> 3;
  const int m0 = (loc / 3) * 128;
  const int n0 = (xcd * 3 + loc % 3) * 128;
  const int lr = lane & 15, lg = lane >> 4;

  f32x4 acc[4][4] = {};

  for (int kc = 0; kc < 1024; kc += 32) {
    __syncthreads();
#pragma unroll
    for (int i = 0; i < 2; ++i) {
      int p = t + 256 * i;
      gload_lds16(A + (size_t)(m0 + (p >> 2)) * 1024 + kc + (p & 3) * 8, &As[p * 8]);
    }
#pragma unroll
    for (int i = 0; i < 2; ++i) {
      int p = t + 256 * i;
      gload_lds16(BT + (size_t)(n0 + (p >> 2)) * 1024 + kc + (p & 3) * 8, &Bs[p * 8]);
    }
    __syncthreads();

    short8 af[4], bf[4];
#pragma unroll
    for (int mf = 0; mf < 4; ++mf)
      af[mf] = *(const short8*)&As[(wr * 64 + mf * 16 + lr) * 32 + lg * 8];
#pragma unroll
    for (int nf = 0; nf < 4; ++nf)
      bf[nf] = *(const short8*)&Bs[(wc * 64 + nf * 16 + lr) * 32 + lg * 8];
#pragma unroll
    for (int mf = 0; mf < 4; ++mf)
#pragma unroll
      for (int nf = 0; nf < 4; ++nf)
        acc[mf][nf] = __builtin_amdgcn_mfma_f32_16x16x32_bf16(af[mf], bf[nf], acc[mf][nf], 0, 0, 0);
  }

#pragma unroll
  for (int mf = 0; mf < 4; ++mf) {
#pragma unroll
    for (int nf = 0; nf < 4; ++nf) {
#pragma unroll
      for (int r = 0; r < 4; ++r) {
        int row = m0 + wr * 64 + mf * 16 + lg * 4 + r;
        int col = n0 + wc * 64 + nf * 16 + lr;
        float v = acc[mf][nf][r];
        int b = row >> 10, tt = row & 1023;
        if (col < 1024) {
          qb[(size_t)row * HD + col] = f2b((v + b0[col]) * (SCALE * SCALE * LOG2E));
        } else if (col < 2048) {
          int hd = col - 1024;
          kbp[(size_t)(b * 1024 + tt) * 1024 + hd] = f2b(v + b1[hd]);
        } else {
          int hd = col - 2048;
          vb[(size_t)(b * 1024 + tt) * 1024 + hd] = f2b(v + b2[hd]);
        }
      }
    }
  }
}

// ---------- fused post-gemm: kvout f32 expand + kt repack | vt repack (transposed) ----------
__global__ __launch_bounds__(256) void post_gemm(const u16* __restrict__ kbp, const u16* __restrict__ vbp,
                                                 float* __restrict__ kvout, u16* __restrict__ kt,
                                                 u16* __restrict__ vt) {
  int bx = blockIdx.x;
  if (bx < 2048) {  // kv_expand + kt repack
    int i = bx * 256 + threadIdx.x;
    int hd8 = i & 127, tt = (i >> 7) & 1023, b = i >> 17;
    size_t src = ((size_t)(b * 1024 + tt)) * 1024 + (size_t)hd8 * 8;
    short8 k8 = *(const short8*)&kbp[src];
    short8 v8 = *(const short8*)&vbp[src];
    float4 k0, k1, v0, v1;
#pragma unroll
    for (int e = 0; e < 4; ++e) {
      ((float*)&k0)[e] = b2f((u16)k8[e]); ((float*)&k1)[e] = b2f((u16)k8[e + 4]);
      ((float*)&v0)[e] = b2f((u16)v8[e]); ((float*)&v1)[e] = b2f((u16)v8[e + 4]);
    }
    float* kdst = kvout + (((size_t)(b * 1024 + tt) * 2 + 0) * 1024) + hd8 * 8;
    float* vdst = kvout + (((size_t)(b * 1024 + tt) * 2 + 1) * 1024) + hd8 * 8;
    ((float4*)kdst)[0] = k0; ((float4*)kdst)[1] = k1;
    ((float4*)vdst)[0] = v0; ((float4*)vdst)[1] = v1;
    int h = hd8 >> 3, d0 = (hd8 & 7) * 8;
    int jc = 16 + (tt >> 6), jl = tt & 63;
    u16* ktdst = kt + (((size_t)(b * 16 + h) * 32 + jc) * 4096) + jl * 64 + d0;
    *(short8*)ktdst = k8;
  } else {  // trans_vnew: vb -> vt tiles jc 16..31
    __shared__ u16 Vl[64 * 72];
    int bxx = bx - 2048;
    int jcl = bxx & 15, h = (bxx >> 4) & 15, b = bxx >> 8;
    int jc = 16 + jcl;
    int t = threadIdx.x;
    int t0 = jcl * 64;
#pragma unroll
    for (int it = 0; it < 2; ++it) {
      int p = t + 256 * it;
      int j = p >> 3, d8 = p & 7;
      *(short8*)&Vl[j * 72 + d8 * 8] =
          *(const short8*)&vbp[((size_t)b * 1024 + t0 + j) * 1024 + h * 64 + d8 * 8];
    }
    __syncthreads();
#pragma unroll
    for (int it = 0; it < 2; ++it) {
      int p = t + 256 * it;
      int d = p >> 3, j8 = p & 7;
      short8 o;
#pragma unroll
      for (int e = 0; e < 8; ++e) o[e] = (short)Vl[(j8 * 8 + e) * 72 + d];
      u16* dst = vt + (((size_t)(b * 16 + h) * 32 + jc) * 4096) + d * 64 + j8 * 8;
      *(short8*)dst = o;
    }
  }
}

// ---------- out-proj GEMM: 64x128 tiles, 512 blocks ----------
__global__ __launch_bounds__(256) void gemm_out(
    const u16* __restrict__ A, const u16* __restrict__ BT,
    const float* __restrict__ bias, float* __restrict__ outf) {
  __shared__ __align__(16) u16 As[64 * 32];
  __shared__ __align__(16) u16 Bs[128 * 32];
  const int t = threadIdx.x;
  const int lane = t & 63, wv = t >> 6;
  const int wr = wv >> 1, wc = wv & 1;
  const int m0 = (blockIdx.x >> 3) * 64;
  const int n0 = (blockIdx.x & 7) * 128;
  const int lr = lane & 15, lg = lane >> 4;

  f32x4 acc[2][4] = {};

  for (int kc = 0; kc < 1024; kc += 32) {
    __syncthreads();
    gload_lds16(A + (size_t)(m0 + (t >> 2)) * 1024 + kc + (t & 3) * 8, &As[t * 8]);
#pragma unroll
    for (int i = 0; i < 2; ++i) {
      int p = t + 256 * i;
      gload_lds16(BT + (size_t)(n0 + (p >> 2)) * 1024 + kc + (p & 3) * 8, &Bs[p * 8]);
    }
    __syncthreads();

    short8 af[2], bf[4];
#pragma unroll
    for (int mf = 0; mf < 2; ++mf)
      af[mf] = *(const short8*)&As[(wr * 32 + mf * 16 + lr) * 32 + lg * 8];
#pragma unroll
    for (int nf = 0; nf < 4; ++nf)
      bf[nf] = *(const short8*)&Bs[(wc * 64 + nf * 16 + lr) * 32 + lg * 8];
#pragma unroll
    for (int mf = 0; mf < 2; ++mf)
#pragma unroll
      for (int nf = 0; nf < 4; ++nf)
        acc[mf][nf] = __builtin_amdgcn_mfma_f32_16x16x32_bf16(af[mf], bf[nf], acc[mf][nf], 0, 0, 0);
  }

#pragma unroll
  for (int mf = 0; mf < 2; ++mf)
#pragma unroll
    for (int nf = 0; nf < 4; ++nf)
#pragma unroll
      for (int r = 0; r < 4; ++r) {
        int row = m0 + wr * 32 + mf * 16 + lg * 4 + r;
        int col = n0 + wc * 64 + nf * 16 + lr;
        outf[(size_t)row * E_ + col] = acc[mf][nf][r] + bias[col];
      }
}

// ---------- flash attention: NO K/V staging (L2-direct), P-only LDS, zero barriers ----------
__global__ __launch_bounds__(256) void attn_kernel(
    const u16* __restrict__ qb, const u16* __restrict__ kt, const u16* __restrict__ vt,
    const float* __restrict__ rel, u16* __restrict__ aout) {
  __shared__ __align__(16) u16 Pl[4096];  // 8 KB only -> occupancy VGPR-bound
  const int bx = blockIdx.x;
  // XCD pinning: 4 b-variants of one (h,qt) share an XCD -> rel + kt/vt slices L2-resident
  const int xcd = bx & 7, s = bx >> 3;
  const int b = s & 3, key = (s >> 2) * 8 + xcd;
  const int h = key & 15, qt = key >> 4;
  const int i0 = qt * 64;
  const int t = threadIdx.x, lane = t & 63, w = t >> 6;
  const int lr = lane & 15, lg = lane >> 4;
  const int swz = (lr & 7) << 3;  // P-tile LDS swizzle only
  const float RC = SCALE * LOG2E;

  const u16* ktb = kt + (size_t)(b * 16 + h) * 32 * 4096;
  const u16* vtb = vt + (size_t)(b * 16 + h) * 32 * 4096;
  // swapped layout: lane's q-row is i0 + w*16 + lr for BOTH S^T and rel
  const float* relrow = rel + (size_t)h * T_ * JTOT + (size_t)(i0 + w * 16 + lr) * JTOT + lg * 4;
  const int nch = qt + 17;

  short8 qf[2];
#pragma unroll
  for (int kc = 0; kc < 2; ++kc)
    qf[kc] = *(const short8*)&qb[(size_t)(b * T_ + i0 + w * 16 + lr) * HD + h * 64 + kc * 32 + lg * 8];

  short8 vf5;  // ones column 0 of B: row-sum trick
#pragma unroll
  for (int e = 0; e < 8; ++e) vf5[e] = (lr == 0) ? (short)0x3f80 : (short)0;

  f32x4 o[4] = {};
  f32x4 o5 = {};   // row-sum accumulator (lanes lr==0)
  float mrow = -__builtin_inff();  // running max for q-row i0+w*16+lr (uniform across lg)

  for (int jc = 0; jc < nch; ++jc) {
    const u16* kbase = ktb + (size_t)jc * 4096;  // [64 j][64 d]
    const u16* vbase = vtb + (size_t)jc * 4096;  // [64 d][64 j]

    float4 rl[4];
#pragma unroll
    for (int nf = 0; nf < 4; ++nf)
      rl[nf] = *(const float4*)(relrow + jc * 64 + nf * 16);

    // S^T = K·Q (log2 domain): K frags read DIRECT from L2-resident kt
    f32x4 s4[4] = {};
#pragma unroll
    for (int nf = 0; nf < 4; ++nf)
#pragma unroll
      for (int kc = 0; kc < 2; ++kc) {
        short8 kf = *(const short8*)&kbase[(nf * 16 + lr) * 64 + kc * 32 + lg * 8];
        s4[nf] = __builtin_amdgcn_mfma_f32_16x16x32_bf16(kf, qf[kc], s4[nf], 0, 0, 0);
      }

    // logits + in-lane max (16 j's of one q-row per lane)
    float p[4][4], lmax = -__builtin_inff();
    const bool domask = (jc == qt + 16);
#pragma unroll
    for (int nf = 0; nf < 4; ++nf)
#pragma unroll
      for (int r = 0; r < 4; ++r) {
        float v = fmaf(((const float*)&rl[nf])[r], RC, s4[nf][r]);
        if (domask && (nf * 16 + lg * 4 + r) > (w * 16 + lr)) v = -__builtin_inff();
        p[nf][r] = v;
        lmax = fmaxf(lmax, v);
      }

    // defer-max: scalar test; cross-lane only on rescale
    const bool dores = !__all(lmax - mrow <= 11.0f);
    if (dores) {
      float ch = fmaxf(lmax, __shfl_xor(lmax, 16, 64));
      ch = fmaxf(ch, __shfl_xor(ch, 32, 64));  // row max (uniform across lg)
      float nm = fmaxf(mrow, ch);
      float sc = fexp2(mrow - nm);
      mrow = nm;
      float sco[4];
#pragma unroll
      for (int r = 0; r < 4; ++r) sco[r] = __shfl(sc, lg * 4 + r, 64);
#pragma unroll
      for (int nf = 0; nf < 4; ++nf)
#pragma unroll
        for (int r = 0; r < 4; ++r) o[nf][r] *= sco[r];
#pragma unroll
      for (int r = 0; r < 4; ++r) o5[r] *= sco[r];
    }

    // P = exp2(p - m) -> bf16 pairs -> wave-private swizzled LDS (8 b32 writes)
    {
      u32* plrow = (u32*)&Pl[(w * 16 + lr) * 64];
#pragma unroll
      for (int nf = 0; nf < 4; ++nf) {
        float e0 = fexp2(p[nf][0] - mrow), e1 = fexp2(p[nf][1] - mrow);
        float e2 = fexp2(p[nf][2] - mrow), e3 = fexp2(p[nf][3] - mrow);
        u32 w0 = cvtpk(e0, e1), w1 = cvtpk(e2, e3);
        plrow[((nf * 16 + lg * 4 + 0) ^ swz) >> 1] = w0;
        plrow[((nf * 16 + lg * 4 + 2) ^ swz) >> 1] = w1;
      }
    }

    // O += P·V: V frags read DIRECT from L2-resident vt; ones-col MFMA -> row-sum
#pragma unroll
    for (int kc = 0; kc < 2; ++kc) {
      short8 pa = *(const short8*)&Pl[(w * 16 + lr) * 64 + ((kc * 32 + lg * 8) ^ swz)];
#pragma unroll
      for (int nf = 0; nf < 4; ++nf) {
        short8 vf = *(const short8*)&vbase[(nf * 16 + lr) * 64 + kc * 32 + lg * 8];
        o[nf] = __builtin_amdgcn_mfma_f32_16x16x32_bf16(pa, vf, o[nf], 0, 0, 0);
      }
      o5 = __builtin_amdgcn_mfma_f32_16x16x32_bf16(pa, vf5, o5, 0, 0, 0);
    }
  }

  float inv[4];
#pragma unroll
  for (int r = 0; r < 4; ++r)
    inv[r] = 1.0f / __shfl(o5[r], lane & 48, 64);
#pragma unroll
  for (int nf = 0; nf < 4; ++nf)
#pragma unroll
    for (int r = 0; r < 4; ++r) {
      int i = i0 + w * 16 + lg * 4 + r, d = nf * 16 + lr;
      aout[(size_t)(b * T_ + i) * HD + h * 64 + d] = f2b_fast(o[nf][r] * inv[r]);
    }
}

// ---------- launch ----------
extern "C" void kernel_launch(void* const* d_in, const int* in_sizes, int n_in,
                              void* d_out, int out_size, void* d_ws, size_t ws_size,
                              hipStream_t stream) {
  const float* x  = (const float*)d_in[0];
  const float* xl = (const float*)d_in[1];
  const float* rel = (const float*)d_in[2];
  const float* Wq = (const float*)d_in[3];
  const float* bq = (const float*)d_in[4];
  const float* Wk = (const float*)d_in[5];
  const float* bk = (const float*)d_in[6];
  const float* Wv = (const float*)d_in[7];
  const float* bv = (const float*)d_in[8];
  const float* Wo = (const float*)d_in[9];
  const float* bo = (const float*)d_in[10];

  float* out = (float*)d_out;
  float* kvout = out + (size_t)B_ * T_ * E_;

  char* ws = (char*)d_ws;
  u16* xb    = (u16*)ws; ws += (size_t)4096 * 1024 * 2;
  u16* wqkvT = (u16*)ws; ws += (size_t)3072 * 1024 * 2;
  u16* woT   = (u16*)ws; ws += (size_t)1024 * 1024 * 2;
  u16* qbuf  = (u16*)ws; ws += (size_t)4096 * 1024 * 2;
  u16* kt    = (u16*)ws; ws += (size_t)B_ * NH * 32 * 4096 * 2;
  u16* vt    = (u16*)ws; ws += (size_t)B_ * NH * 32 * 4096 * 2;
  u16* vbn   = (u16*)ws; ws += (size_t)4096 * 1024 * 2;
  u16* kbp   = (u16*)ws; ws += (size_t)4096 * 1024 * 2;
  u16* aout  = (u16*)ws; ws += (size_t)4096 * 1024 * 2;

  cvt_all<<<6144, 256, 0, stream>>>(x, Wq, Wk, Wv, Wo, xl, xb, wqkvT, woT, kt, vt);
  gemm_qkv<<<768, 256, 0, stream>>>(xb, wqkvT, bq, bk, bv, qbuf, kbp, vbn);
  post_gemm<<<3072, 256, 0, stream>>>(kbp, vbn, kvout, kt, vt);
  attn_kernel<<<1024, 256, 0, stream>>>(qbuf, kt, vt, rel, aout);
  gemm_out<<<512, 256, 0, stream>>>(aout, woT, bo, out);
}

// Round 13
// 203.067 us; speedup vs baseline: 1.8153x; 1.8153x over previous
//
#include <hip/hip_runtime.h>
#include <hip/hip_bf16.h>

typedef unsigned short u16;
typedef unsigned int u32;
typedef __attribute__((ext_vector_type(8))) short short8;
typedef __attribute__((ext_vector_type(4))) float f32x4;

#define B_ 4
#define T_ 1024
#define E_ 1024
#define NH 16
#define HD 1024
#define JTOT 2048
#define SCALE 0.125f
#define LOG2E 1.44269504f

// ---------- helpers ----------
__device__ __forceinline__ u16 f2b(float f) {
  u32 x = __float_as_uint(f);
  u32 r = (x + 0x7fffu + ((x >> 16) & 1u)) >> 16;  // RNE
  return (u16)r;
}
__device__ __forceinline__ u16 f2b_fast(float f) {  // round-half-up (2 ops)
  return (u16)((__float_as_uint(f) + 0x8000u) >> 16);
}
__device__ __forceinline__ float b2f(u16 b) {
  return __uint_as_float((u32)b << 16);
}
__device__ __forceinline__ float fexp2(float x) {
  float r;
  asm("v_exp_f32 %0, %1" : "=v"(r) : "v"(x));
  return r;
}
__device__ __forceinline__ u32 cvtpk(float lo, float hi) {  // bf16 pair: lo in low 16
  u32 r;
  asm("v_cvt_pk_bf16_f32 %0, %1, %2" : "=v"(r) : "v"(lo), "v"(hi));
  return r;
}

__device__ __forceinline__ void gload_lds16(const void* g, void* l) {
  __builtin_amdgcn_global_load_lds((const __attribute__((address_space(1))) u32*)g,
                                   (__attribute__((address_space(3))) u32*)l, 16, 0, 0);
}

__device__ __forceinline__ short8 pack8(float4 f0, float4 f1) {
  short8 o;
  o[0] = (short)f2b(f0.x); o[1] = (short)f2b(f0.y);
  o[2] = (short)f2b(f0.z); o[3] = (short)f2b(f0.w);
  o[4] = (short)f2b(f1.x); o[5] = (short)f2b(f1.y);
  o[6] = (short)f2b(f1.z); o[7] = (short)f2b(f1.w);
  return o;
}

// ---------- fused conversions: x->bf16 | W-transpose x4 | xl->kt | xl->vT ----------
// kt/vt tiles octet-SWIZZLED (R10 attn read layout)
__global__ __launch_bounds__(256) void cvt_all(
    const float* __restrict__ x, const float* __restrict__ Wq, const float* __restrict__ Wk,
    const float* __restrict__ Wv, const float* __restrict__ Wo, const float* __restrict__ xl,
    u16* __restrict__ xb, u16* __restrict__ wqkvT, u16* __restrict__ woT,
    u16* __restrict__ kt, u16* __restrict__ vt) {
  int bx = blockIdx.x;
  if (bx < 2048) {  // x -> xb (bf16)
    int i = bx * 256 + threadIdx.x;
    const float4* p = (const float4*)x + (size_t)i * 2;
    ((short8*)xb)[i] = pack8(p[0], p[1]);
  } else if (bx < 3072) {  // 4x W -> WT bf16 transposed
    __shared__ float tile[64][65];
    int idx = bx - 2048;
    int z = idx >> 8, yy = (idx >> 4) & 15, xx = idx & 15;
    const float* W;
    u16* WT;
    if (z == 0) { W = Wq; WT = wqkvT; }
    else if (z == 1) { W = Wk; WT = wqkvT + (size_t)1024 * 1024; }
    else if (z == 2) { W = Wv; WT = wqkvT + (size_t)2048 * 1024; }
    else { W = Wo; WT = woT; }
    int t = threadIdx.x;
    int r0 = yy * 64, c0 = xx * 64;
#pragma unroll
    for (int i = 0; i < 16; ++i) {
      int r = i * 4 + (t >> 6), c = t & 63;
      tile[r][c] = W[(size_t)(r0 + r) * 1024 + c0 + c];
    }
    __syncthreads();
#pragma unroll
    for (int i = 0; i < 16; ++i) {
      int r = i * 4 + (t >> 6), c = t & 63;
      WT[(size_t)(c0 + r) * 1024 + r0 + c] = f2b(tile[c][r]);
    }
  } else if (bx < 5120) {  // xl k-half -> kt tiles jc 0..15 [64 j][64 d ^ swz]
    int i = (bx - 3072) * 256 + threadIdx.x;
    int hd8 = i & 127, j = (i >> 7) & 1023, b = i >> 17;
    const float4* p = (const float4*)(xl + ((((size_t)b * 1024 + j) * 2 + 0) * 1024 + (size_t)hd8 * 8));
    short8 o = pack8(p[0], p[1]);
    int h = hd8 >> 3, d0 = (hd8 & 7) * 8;
    int jc = j >> 6, jl = j & 63;
    u16* dst = kt + (((size_t)(b * 16 + h) * 32 + jc) * 4096) + jl * 64 + (d0 ^ ((jl & 7) << 3));
    *(short8*)dst = o;
  } else {  // xl v-half -> vt tiles jc 0..15 [64 d][64 j ^ swz] (transposed)
    __shared__ u16 Vl[64 * 72];
    int bxx = bx - 5120;
    int jc = bxx & 15, h = (bxx >> 4) & 15, b = bxx >> 8;
    int t = threadIdx.x;
    int j0 = jc * 64;
#pragma unroll
    for (int it = 0; it < 2; ++it) {
      int p = t + 256 * it;
      int j = p >> 3, d8 = p & 7;
      const float4* src = (const float4*)(xl + ((((size_t)b * 1024 + j0 + j) * 2 + 1) * 1024 + h * 64 + (size_t)d8 * 8));
      *(short8*)&Vl[j * 72 + d8 * 8] = pack8(src[0], src[1]);
    }
    __syncthreads();
#pragma unroll
    for (int it = 0; it < 2; ++it) {
      int p = t + 256 * it;
      int d = p >> 3, j8 = p & 7;
      short8 o;
#pragma unroll
      for (int e = 0; e < 8; ++e) o[e] = (short)Vl[(j8 * 8 + e) * 72 + d];
      u16* dst = vt + (((size_t)(b * 16 + h) * 32 + jc) * 4096) + d * 64 + ((j8 * 8) ^ ((d & 7) << 3));
      *(short8*)dst = o;
    }
  }
}

// ---------- QKV GEMM: 128x128 tiles, coalesced-only epilogue, XCD column strips ----------
__global__ __launch_bounds__(256) void gemm_qkv(
    const u16* __restrict__ A, const u16* __restrict__ BT,
    const float* __restrict__ b0, const float* __restrict__ b1, const float* __restrict__ b2,
    u16* __restrict__ qb, u16* __restrict__ kbp, u16* __restrict__ vb) {
  __shared__ __align__(16) u16 As[128 * 32];
  __shared__ __align__(16) u16 Bs[128 * 32];
  const int t = threadIdx.x;
  const int lane = t & 63, wv = t >> 6;
  const int wr = wv >> 1, wc = wv & 1;
  const int xcd = blockIdx.x & 7, loc = blockIdx.x >> 3;
  const int m0 = (loc / 3) * 128;
  const int n0 = (xcd * 3 + loc % 3) * 128;
  const int lr = lane & 15, lg = lane >> 4;

  f32x4 acc[4][4] = {};

  for (int kc = 0; kc < 1024; kc += 32) {
    __syncthreads();
#pragma unroll
    for (int i = 0; i < 2; ++i) {
      int p = t + 256 * i;
      gload_lds16(A + (size_t)(m0 + (p >> 2)) * 1024 + kc + (p & 3) * 8, &As[p * 8]);
    }
#pragma unroll
    for (int i = 0; i < 2; ++i) {
      int p = t + 256 * i;
      gload_lds16(BT + (size_t)(n0 + (p >> 2)) * 1024 + kc + (p & 3) * 8, &Bs[p * 8]);
    }
    __syncthreads();

    short8 af[4], bf[4];
#pragma unroll
    for (int mf = 0; mf < 4; ++mf)
      af[mf] = *(const short8*)&As[(wr * 64 + mf * 16 + lr) * 32 + lg * 8];
#pragma unroll
    for (int nf = 0; nf < 4; ++nf)
      bf[nf] = *(const short8*)&Bs[(wc * 64 + nf * 16 + lr) * 32 + lg * 8];
#pragma unroll
    for (int mf = 0; mf < 4; ++mf)
#pragma unroll
      for (int nf = 0; nf < 4; ++nf)
        acc[mf][nf] = __builtin_amdgcn_mfma_f32_16x16x32_bf16(af[mf], bf[nf], acc[mf][nf], 0, 0, 0);
  }

#pragma unroll
  for (int mf = 0; mf < 4; ++mf) {
#pragma unroll
    for (int nf = 0; nf < 4; ++nf) {
#pragma unroll
      for (int r = 0; r < 4; ++r) {
        int row = m0 + wr * 64 + mf * 16 + lg * 4 + r;
        int col = n0 + wc * 64 + nf * 16 + lr;
        float v = acc[mf][nf][r];
        int b = row >> 10, tt = row & 1023;
        if (col < 1024) {
          qb[(size_t)row * HD + col] = f2b((v + b0[col]) * (SCALE * SCALE * LOG2E));
        } else if (col < 2048) {
          int hd = col - 1024;
          kbp[(size_t)(b * 1024 + tt) * 1024 + hd] = f2b(v + b1[hd]);
        } else {
          int hd = col - 2048;
          vb[(size_t)(b * 1024 + tt) * 1024 + hd] = f2b(v + b2[hd]);
        }
      }
    }
  }
}

// ---------- fused post-gemm: kvout f32 expand + kt repack | vt repack (transposed) ----------
__global__ __launch_bounds__(256) void post_gemm(const u16* __restrict__ kbp, const u16* __restrict__ vbp,
                                                 float* __restrict__ kvout, u16* __restrict__ kt,
                                                 u16* __restrict__ vt) {
  int bx = blockIdx.x;
  if (bx < 2048) {  // kv_expand + kt repack (octet-swizzled)
    int i = bx * 256 + threadIdx.x;
    int hd8 = i & 127, tt = (i >> 7) & 1023, b = i >> 17;
    size_t src = ((size_t)(b * 1024 + tt)) * 1024 + (size_t)hd8 * 8;
    short8 k8 = *(const short8*)&kbp[src];
    short8 v8 = *(const short8*)&vbp[src];
    float4 k0, k1, v0, v1;
#pragma unroll
    for (int e = 0; e < 4; ++e) {
      ((float*)&k0)[e] = b2f((u16)k8[e]); ((float*)&k1)[e] = b2f((u16)k8[e + 4]);
      ((float*)&v0)[e] = b2f((u16)v8[e]); ((float*)&v1)[e] = b2f((u16)v8[e + 4]);
    }
    float* kdst = kvout + (((size_t)(b * 1024 + tt) * 2 + 0) * 1024) + hd8 * 8;
    float* vdst = kvout + (((size_t)(b * 1024 + tt) * 2 + 1) * 1024) + hd8 * 8;
    ((float4*)kdst)[0] = k0; ((float4*)kdst)[1] = k1;
    ((float4*)vdst)[0] = v0; ((float4*)vdst)[1] = v1;
    int h = hd8 >> 3, d0 = (hd8 & 7) * 8;
    int jc = 16 + (tt >> 6), jl = tt & 63;
    u16* ktdst = kt + (((size_t)(b * 16 + h) * 32 + jc) * 4096) + jl * 64 + (d0 ^ ((jl & 7) << 3));
    *(short8*)ktdst = k8;
  } else {  // trans_vnew: vb -> vt tiles jc 16..31 (transposed + octet-swizzled)
    __shared__ u16 Vl[64 * 72];
    int bxx = bx - 2048;
    int jcl = bxx & 15, h = (bxx >> 4) & 15, b = bxx >> 8;
    int jc = 16 + jcl;
    int t = threadIdx.x;
    int t0 = jcl * 64;
#pragma unroll
    for (int it = 0; it < 2; ++it) {
      int p = t + 256 * it;
      int j = p >> 3, d8 = p & 7;
      *(short8*)&Vl[j * 72 + d8 * 8] =
          *(const short8*)&vbp[((size_t)b * 1024 + t0 + j) * 1024 + h * 64 + d8 * 8];
    }
    __syncthreads();
#pragma unroll
    for (int it = 0; it < 2; ++it) {
      int p = t + 256 * it;
      int d = p >> 3, j8 = p & 7;
      short8 o;
#pragma unroll
      for (int e = 0; e < 8; ++e) o[e] = (short)Vl[(j8 * 8 + e) * 72 + d];
      u16* dst = vt + (((size_t)(b * 16 + h) * 32 + jc) * 4096) + d * 64 + ((j8 * 8) ^ ((d & 7) << 3));
      *(short8*)dst = o;
    }
  }
}

// ---------- out-proj GEMM: 64x128 tiles, 512 blocks ----------
__global__ __launch_bounds__(256) void gemm_out(
    const u16* __restrict__ A, const u16* __restrict__ BT,
    const float* __restrict__ bias, float* __restrict__ outf) {
  __shared__ __align__(16) u16 As[64 * 32];
  __shared__ __align__(16) u16 Bs[128 * 32];
  const int t = threadIdx.x;
  const int lane = t & 63, wv = t >> 6;
  const int wr = wv >> 1, wc = wv & 1;
  const int m0 = (blockIdx.x >> 3) * 64;
  const int n0 = (blockIdx.x & 7) * 128;
  const int lr = lane & 15, lg = lane >> 4;

  f32x4 acc[2][4] = {};

  for (int kc = 0; kc < 1024; kc += 32) {
    __syncthreads();
    gload_lds16(A + (size_t)(m0 + (t >> 2)) * 1024 + kc + (t & 3) * 8, &As[t * 8]);
#pragma unroll
    for (int i = 0; i < 2; ++i) {
      int p = t + 256 * i;
      gload_lds16(BT + (size_t)(n0 + (p >> 2)) * 1024 + kc + (p & 3) * 8, &Bs[p * 8]);
    }
    __syncthreads();

    short8 af[2], bf[4];
#pragma unroll
    for (int mf = 0; mf < 2; ++mf)
      af[mf] = *(const short8*)&As[(wr * 32 + mf * 16 + lr) * 32 + lg * 8];
#pragma unroll
    for (int nf = 0; nf < 4; ++nf)
      bf[nf] = *(const short8*)&Bs[(wc * 64 + nf * 16 + lr) * 32 + lg * 8];
#pragma unroll
    for (int mf = 0; mf < 2; ++mf)
#pragma unroll
      for (int nf = 0; nf < 4; ++nf)
        acc[mf][nf] = __builtin_amdgcn_mfma_f32_16x16x32_bf16(af[mf], bf[nf], acc[mf][nf], 0, 0, 0);
  }

#pragma unroll
  for (int mf = 0; mf < 2; ++mf)
#pragma unroll
    for (int nf = 0; nf < 4; ++nf)
#pragma unroll
      for (int r = 0; r < 4; ++r) {
        int row = m0 + wr * 32 + mf * 16 + lg * 4 + r;
        int col = n0 + wc * 64 + nf * 16 + lr;
        outf[(size_t)row * E_ + col] = acc[mf][nf][r] + bias[col];
      }
}

// ---------- flash attention (R10 best-known): swapped QK^T, staged K/V, vmcnt(4) ----------
__global__ __launch_bounds__(256) void attn_kernel(
    const u16* __restrict__ qb, const u16* __restrict__ kt, const u16* __restrict__ vt,
    const float* __restrict__ rel, u16* __restrict__ aout) {
  __shared__ __align__(16) u16 Ks[2][4096];
  __shared__ __align__(16) u16 Vs[2][4096];
  __shared__ __align__(16) u16 Pl[4096];
  const int bx = blockIdx.x;
  // XCD pinning: 4 b-variants of one (h,qt) share an XCD -> rel slice L2-resident
  const int xcd = bx & 7, s = bx >> 3;
  const int b = s & 3, key = (s >> 2) * 8 + xcd;
  const int h = key & 15, qt = key >> 4;
  const int i0 = qt * 64;
  const int t = threadIdx.x, lane = t & 63, w = t >> 6;
  const int lr = lane & 15, lg = lane >> 4;
  const int swz = (lr & 7) << 3;  // row-keyed octet swizzle (K/V and P)
  const float RC = SCALE * LOG2E;

  const u16* ktb = kt + (size_t)(b * 16 + h) * 32 * 4096;
  const u16* vtb = vt + (size_t)(b * 16 + h) * 32 * 4096;
  // swapped layout: lane's q-row is i0 + w*16 + lr for BOTH S^T and rel
  const float* relrow = rel + (size_t)h * T_ * JTOT + (size_t)(i0 + w * 16 + lr) * JTOT + lg * 4;
  const int nch = qt + 17;

  short8 qf[2];
#pragma unroll
  for (int kc = 0; kc < 2; ++kc)
    qf[kc] = *(const short8*)&qb[(size_t)(b * T_ + i0 + w * 16 + lr) * HD + h * 64 + kc * 32 + lg * 8];

  short8 vf5;  // ones column 0 of B: row-sum trick
#pragma unroll
  for (int e = 0; e < 8; ++e) vf5[e] = (lr == 0) ? (short)0x3f80 : (short)0;

  auto stage = [&](int buf, int jc2) {  // 4 VMEM instrs/thread
    const u16* ksrc = ktb + (size_t)jc2 * 4096;
    const u16* vsrc = vtb + (size_t)jc2 * 4096;
    gload_lds16(ksrc + t * 8, &Ks[buf][t * 8]);
    gload_lds16(ksrc + (t + 256) * 8, &Ks[buf][(t + 256) * 8]);
    gload_lds16(vsrc + t * 8, &Vs[buf][t * 8]);
    gload_lds16(vsrc + (t + 256) * 8, &Vs[buf][(t + 256) * 8]);
  };

  auto loadrel = [&](int j0, float4 (&rlf)[4]) {  // 4 VMEM dwordx4 loads/thread
#pragma unroll
    for (int nf = 0; nf < 4; ++nf)
      rlf[nf] = *(const float4*)(relrow + j0 + nf * 16);
  };

  float4 rlA[4], rlB[4];
  stage(0, 0);
  __builtin_amdgcn_sched_barrier(0);  // stage(0) VMEM issued first: vmcnt counting valid
  loadrel(0, rlA);
  loadrel(64, rlB);

  f32x4 o[4] = {};
  f32x4 o5 = {};   // row-sum accumulator (lanes lr==0)
  float mrow = -__builtin_inff();  // running max for q-row i0+w*16+lr (uniform across lg)

  int cur = 0;
  auto chunkfn = [&](int jc, float4 (&rlu)[4]) {
    // outstanding oldest->newest: rel(jc)[4], stage(jc)[4], rel(jc+1)[4]
    // vmcnt(4): drains rel(jc)+stage(jc); rel(jc+1) stays in flight across barrier
    asm volatile("s_waitcnt vmcnt(4)" ::: "memory");
    __builtin_amdgcn_sched_barrier(0);
    asm volatile("s_barrier" ::: "memory");
    if (jc + 1 < nch) stage(cur ^ 1, jc + 1);
    __builtin_amdgcn_sched_barrier(0);

    // S^T = K Q (log2 domain): lane holds S[j=nf*16+lg*4+r][i=lr-row]
    f32x4 s4[4] = {};
#pragma unroll
    for (int nf = 0; nf < 4; ++nf)
#pragma unroll
      for (int kc = 0; kc < 2; ++kc) {
        short8 kf = *(const short8*)&Ks[cur][(nf * 16 + lr) * 64 + ((kc * 32 + lg * 8) ^ swz)];
        s4[nf] = __builtin_amdgcn_mfma_f32_16x16x32_bf16(kf, qf[kc], s4[nf], 0, 0, 0);
      }

    // logits + in-lane max (16 j's of one q-row per lane)
    float p[4][4], lmax = -__builtin_inff();
    const bool domask = (jc == qt + 16);
#pragma unroll
    for (int nf = 0; nf < 4; ++nf)
#pragma unroll
      for (int r = 0; r < 4; ++r) {
        float v = fmaf(((const float*)&rlu[nf])[r], RC, s4[nf][r]);
        if (domask && (nf * 16 + lg * 4 + r) > (w * 16 + lr)) v = -__builtin_inff();
        p[nf][r] = v;
        lmax = fmaxf(lmax, v);
      }
    if (jc + 2 < nch) loadrel((jc + 2) * 64, rlu);  // refill: ~1.5-chunk coverage

    // defer-max: scalar test; cross-lane only on rescale
    const bool dores = !__all(lmax - mrow <= 11.0f);
    if (dores) {
      float ch = fmaxf(lmax, __shfl_xor(lmax, 16, 64));
      ch = fmaxf(ch, __shfl_xor(ch, 32, 64));  // row max (uniform across lg)
      float nm = fmaxf(mrow, ch);
      float sc = fexp2(mrow - nm);
      mrow = nm;
      // redistribute sc to D-layout rows: o rows are i = w*16 + lg*4 + r
      float sco[4];
#pragma unroll
      for (int r = 0; r < 4; ++r) sco[r] = __shfl(sc, lg * 4 + r, 64);
#pragma unroll
      for (int nf = 0; nf < 4; ++nf)
#pragma unroll
        for (int r = 0; r < 4; ++r) o[nf][r] *= sco[r];
#pragma unroll
      for (int r = 0; r < 4; ++r) o5[r] *= sco[r];
    }

    // P = exp2(p - m) -> bf16 pairs -> wave-private swizzled LDS (8 b32 writes)
    {
      u32* plrow = (u32*)&Pl[(w * 16 + lr) * 64];
#pragma unroll
      for (int nf = 0; nf < 4; ++nf) {
        float e0 = fexp2(p[nf][0] - mrow), e1 = fexp2(p[nf][1] - mrow);
        float e2 = fexp2(p[nf][2] - mrow), e3 = fexp2(p[nf][3] - mrow);
        u32 w0 = cvtpk(e0, e1), w1 = cvtpk(e2, e3);
        plrow[((nf * 16 + lg * 4 + 0) ^ swz) >> 1] = w0;
        plrow[((nf * 16 + lg * 4 + 2) ^ swz) >> 1] = w1;
      }
    }

    // O += P @ V; ones-column MFMA accumulates row-sum into o5
#pragma unroll
    for (int kc = 0; kc < 2; ++kc) {
      short8 pa = *(const short8*)&Pl[(w * 16 + lr) * 64 + ((kc * 32 + lg * 8) ^ swz)];
#pragma unroll
      for (int nf = 0; nf < 4; ++nf) {
        short8 vf = *(const short8*)&Vs[cur][(nf * 16 + lr) * 64 + ((kc * 32 + lg * 8) ^ swz)];
        o[nf] = __builtin_amdgcn_mfma_f32_16x16x32_bf16(pa, vf, o[nf], 0, 0, 0);
      }
      o5 = __builtin_amdgcn_mfma_f32_16x16x32_bf16(pa, vf5, o5, 0, 0, 0);
    }
    cur ^= 1;
  };

  int jc = 0;
  for (; jc + 1 < nch; jc += 2) {  // static unroll-2: rlA/rlB never runtime-indexed
    chunkfn(jc, rlA);
    chunkfn(jc + 1, rlB);
  }
  if (jc < nch) chunkfn(jc, rlA);

  float inv[4];
#pragma unroll
  for (int r = 0; r < 4; ++r)
    inv[r] = 1.0f / __shfl(o5[r], lane & 48, 64);
#pragma unroll
  for (int nf = 0; nf < 4; ++nf)
#pragma unroll
    for (int r = 0; r < 4; ++r) {
      int i = i0 + w * 16 + lg * 4 + r, d = nf * 16 + lr;
      aout[(size_t)(b * T_ + i) * HD + h * 64 + d] = f2b_fast(o[nf][r] * inv[r]);
    }
}

// ---------- launch ----------
extern "C" void kernel_launch(void* const* d_in, const int* in_sizes, int n_in,
                              void* d_out, int out_size, void* d_ws, size_t ws_size,
                              hipStream_t stream) {
  const float* x  = (const float*)d_in[0];
  const float* xl = (const float*)d_in[1];
  const float* rel = (const float*)d_in[2];
  const float* Wq = (const float*)d_in[3];
  const float* bq = (const float*)d_in[4];
  const float* Wk = (const float*)d_in[5];
  const float* bk = (const float*)d_in[6];
  const float* Wv = (const float*)d_in[7];
  const float* bv = (const float*)d_in[8];
  const float* Wo = (const float*)d_in[9];
  const float* bo = (const float*)d_in[10];

  float* out = (float*)d_out;
  float* kvout = out + (size_t)B_ * T_ * E_;

  char* ws = (char*)d_ws;
  u16* xb    = (u16*)ws; ws += (size_t)4096 * 1024 * 2;
  u16* wqkvT = (u16*)ws; ws += (size_t)3072 * 1024 * 2;
  u16* woT   = (u16*)ws; ws += (size_t)1024 * 1024 * 2;
  u16* qbuf  = (u16*)ws; ws += (size_t)4096 * 1024 * 2;
  u16* kt    = (u16*)ws; ws += (size_t)B_ * NH * 32 * 4096 * 2;
  u16* vt    = (u16*)ws; ws += (size_t)B_ * NH * 32 * 4096 * 2;
  u16* vbn   = (u16*)ws; ws += (size_t)4096 * 1024 * 2;
  u16* kbp   = (u16*)ws; ws += (size_t)4096 * 1024 * 2;
  u16* aout  = (u16*)ws; ws += (size_t)4096 * 1024 * 2;

  cvt_all<<<6144, 256, 0, stream>>>(x, Wq, Wk, Wv, Wo, xl, xb, wqkvT, woT, kt, vt);
  gemm_qkv<<<768, 256, 0, stream>>>(xb, wqkvT, bq, bk, bv, qbuf, kbp, vbn);
  post_gemm<<<3072, 256, 0, stream>>>(kbp, vbn, kvout, kt, vt);
  attn_kernel<<<1024, 256, 0, stream>>>(qbuf, kt, vt, rel, aout);
  gemm_out<<<512, 256, 0, stream>>>(aout, woT, bo, out);
}